// Round 2
// 825.804 us; speedup vs baseline: 1.2515x; 1.2515x over previous
//
#include <hip/hip_runtime.h>
#include <hip/hip_bf16.h>
#include <math.h>

// ---------------------------------------------------------------------------
// Round 4: fix pipeline-tail race in the 256² 8-wave GEMM.
//   Bug: at the second-to-last K-tile (p2 false, only 4 loads issued),
//   vmcnt(4) left the final tile's chunks 2,3 IN FLIGHT -> stale LDS reads
//   of the last K-tile every launch (absmax 2.4e-4 -> 1.95e-3).
//   Fix: final wait per tile = p2 ? vmcnt(4) : vmcnt(0)  (the only loads
//   allowed to remain in flight are the ones issued for tile+2).
// Everything else identical to round 3.
// ---------------------------------------------------------------------------

typedef __attribute__((ext_vector_type(8))) short short8;   // 8 bf16
typedef __attribute__((ext_vector_type(4))) float floatx4;  // MFMA acc

__device__ __forceinline__ unsigned short f2bf(float x) {
  return __builtin_bit_cast(unsigned short, __float2bfloat16(x));
}
__device__ __forceinline__ float bf2f(unsigned short s) {
  unsigned int u = ((unsigned int)s) << 16;
  return __builtin_bit_cast(float, u);
}

typedef const unsigned int __attribute__((address_space(1))) ga_u32;
typedef unsigned int __attribute__((address_space(3))) lds_u32;
__device__ __forceinline__ void gl_lds16(const void* g, void* l) {
  __builtin_amdgcn_global_load_lds((ga_u32*)g, (lds_u32*)l, 16, 0, 0);
}

// ===========================================================================
// gemm8: C = A(MxK) . B(NxK)^T, bf16 inputs, 256x256 tile, BK=64, 512 thr.
//   8 waves (2 M x 4 N), wave tile 128x64, acc[8][4] of 16x16 frags.
//   LDS 128KB dynamic: A buffers [0,64K) (2x32K dbuf), B buffers [64K,128K).
//   LDS layout swizzled: stored byte(row,k) = row*128 + ((2k) ^ ((row&7)<<4)).
//   Staged via global_load_lds w/ pre-swizzled global source (linear dest).
//   Per K-tile: 4 phases {ds_read quad frags | stage 1 future chunk | barrier
//   | setprio1 | 16 MFMA | setprio0 | barrier}; counted vmcnt once per tile.
// EPI: 1 = bf16 out (alpha, opt bias, per-z strided)
//      3 = bf16 out transposed per batch (+bias)   [V projection]
//      4 = split bf16 h+l out                      [attended]
// ===========================================================================
template <int EPI>
__global__ __launch_bounds__(512, 2) void gemm8(
    const unsigned short* __restrict__ Ah,
    const unsigned short* __restrict__ Bh, void* __restrict__ Cp,
    unsigned short* __restrict__ Cl, const float* __restrict__ bias,
    float alpha, int M, int N, int K, int Mt, long long sA, long long sB,
    long long sC) {
  extern __shared__ char smem[];

  // ---- XCD-contiguous block swizzle (all launches have nwg % 8 == 0) ----
  const int gx = gridDim.x;
  const int gxy = gx * gridDim.y;
  const int nwg = gxy * gridDim.z;
  const int orig = blockIdx.z * gxy + blockIdx.y * gx + blockIdx.x;
  const int wg = (orig & 7) * (nwg >> 3) + (orig >> 3);
  const int zb_i = wg / gxy;
  const int rem = wg - zb_i * gxy;
  const int by = rem / gx;
  const int bx = rem - by * gx;
  const int m0 = by * 256, n0 = bx * 256;
  const long long zb = zb_i;

  const unsigned short* Ag = Ah + zb * sA;
  const unsigned short* Bg = Bh + zb * sB;

  const int t = threadIdx.x;
  // ---- staging: thread t loads 16B; LDS dest linear (chunk*8192 + t*16),
  //      global source carries the inverse swizzle ----
  const int srow = t >> 3;                              // row within 64-row chunk
  const int skw = ((t & 7) << 3) ^ ((srow & 7) << 3);   // swizzled k element
  const unsigned short* aS = Ag + (long long)(m0 + srow) * K + skw;
  const unsigned short* bS = Bg + (long long)(n0 + srow) * K + skw;
  char* dstA = smem + t * 16;
  char* dstB = smem + 65536 + t * 16;

  // ---- fragment-read bases (swizzled) ----
  const int lane = t & 63;
  const int wv = t >> 6, wy = wv >> 2, wx = wv & 3;  // 2 x 4 waves
  const int lm = lane & 15, q = lane >> 4;
  const int x0 = (q << 4) ^ ((lm & 7) << 4);
  const int aB0 = (wy * 128 + lm) * 128;
  const int bB0 = 65536 + (wx * 64 + lm) * 128;
  const int aRd0 = aB0 + x0, aRd1 = aB0 + (x0 ^ 64);  // kh = 0 / 1
  const int bRd0 = bB0 + x0, bRd1 = bB0 + (x0 ^ 64);

  floatx4 acc[8][4];
#pragma unroll
  for (int i = 0; i < 8; ++i)
#pragma unroll
    for (int j = 0; j < 4; ++j) acc[i][j] = (floatx4)(0.0f);

  short8 fa[4][2];     // current m-half A frags [mt][kh]
  short8 fb[2][2][2];  // both n-halves B frags [nh][nt][kh]

  // ---- prologue: tile0 chunks 0..3, tile1 chunks 0,1 (12 loads) ----
#pragma unroll
  for (int c = 0; c < 4; ++c) {
    gl_lds16(aS + (long long)(c * 64) * K, dstA + c * 8192);
    gl_lds16(bS + (long long)(c * 64) * K, dstB + c * 8192);
  }
  gl_lds16(aS + 64, dstA + 32768);
  gl_lds16(bS + 64, dstB + 32768);
  gl_lds16(aS + 64LL * K + 64, dstA + 32768 + 8192);
  gl_lds16(bS + 64LL * K + 64, dstB + 32768 + 8192);
  asm volatile("s_waitcnt vmcnt(4)" ::: "memory");  // tile0 resident
  __builtin_amdgcn_s_barrier();

  auto tile = [&](int kt, int bo, int nbo) {
    const bool p1 = (kt + 64) < K;   // stage tile+1 chunks 2,3 (into nbo)
    const bool p2 = (kt + 128) < K;  // stage tile+2 chunks 0,1 (into bo)
    // ---------------- phase 0: quad(m-half0, n-half0) ----------------
#pragma unroll
    for (int mt = 0; mt < 4; ++mt) {
      fa[mt][0] = *(const short8*)(smem + (bo + aRd0 + mt * 2048));
      fa[mt][1] = *(const short8*)(smem + (bo + aRd1 + mt * 2048));
    }
#pragma unroll
    for (int nt = 0; nt < 2; ++nt) {
      fb[0][nt][0] = *(const short8*)(smem + (bo + bRd0 + nt * 2048));
      fb[0][nt][1] = *(const short8*)(smem + (bo + bRd1 + nt * 2048));
    }
    if (p1) {
      gl_lds16(aS + 128LL * K + (kt + 64), dstA + nbo + 16384);
      gl_lds16(bS + 128LL * K + (kt + 64), dstB + nbo + 16384);
    }
    __builtin_amdgcn_s_barrier();
    __builtin_amdgcn_s_setprio(1);
#pragma unroll
    for (int mt = 0; mt < 4; ++mt)
#pragma unroll
      for (int nt = 0; nt < 2; ++nt) {
        acc[mt][nt] = __builtin_amdgcn_mfma_f32_16x16x32_bf16(
            fa[mt][0], fb[0][nt][0], acc[mt][nt], 0, 0, 0);
        acc[mt][nt] = __builtin_amdgcn_mfma_f32_16x16x32_bf16(
            fa[mt][1], fb[0][nt][1], acc[mt][nt], 0, 0, 0);
      }
    __builtin_amdgcn_s_setprio(0);
    __builtin_amdgcn_s_barrier();
    // ---------------- phase 1: quad(m-half0, n-half1) ----------------
#pragma unroll
    for (int nt = 0; nt < 2; ++nt) {
      fb[1][nt][0] = *(const short8*)(smem + (bo + bRd0 + 4096 + nt * 2048));
      fb[1][nt][1] = *(const short8*)(smem + (bo + bRd1 + 4096 + nt * 2048));
    }
    if (p1) {
      gl_lds16(aS + 192LL * K + (kt + 64), dstA + nbo + 24576);
      gl_lds16(bS + 192LL * K + (kt + 64), dstB + nbo + 24576);
    }
    __builtin_amdgcn_s_barrier();
    __builtin_amdgcn_s_setprio(1);
#pragma unroll
    for (int mt = 0; mt < 4; ++mt)
#pragma unroll
      for (int nt = 0; nt < 2; ++nt) {
        acc[mt][2 + nt] = __builtin_amdgcn_mfma_f32_16x16x32_bf16(
            fa[mt][0], fb[1][nt][0], acc[mt][2 + nt], 0, 0, 0);
        acc[mt][2 + nt] = __builtin_amdgcn_mfma_f32_16x16x32_bf16(
            fa[mt][1], fb[1][nt][1], acc[mt][2 + nt], 0, 0, 0);
      }
    __builtin_amdgcn_s_setprio(0);
    __builtin_amdgcn_s_barrier();
    // ---------------- phase 2: quad(m-half1, n-half0) ----------------
#pragma unroll
    for (int mt = 0; mt < 4; ++mt) {
      fa[mt][0] = *(const short8*)(smem + (bo + aRd0 + 8192 + mt * 2048));
      fa[mt][1] = *(const short8*)(smem + (bo + aRd1 + 8192 + mt * 2048));
    }
    if (p2) {  // chunk0 of this buffer is dead (read only in phase 0/1)
      gl_lds16(aS + (kt + 128), dstA + bo);
      gl_lds16(bS + (kt + 128), dstB + bo);
    }
    __builtin_amdgcn_s_barrier();
    __builtin_amdgcn_s_setprio(1);
#pragma unroll
    for (int mt = 0; mt < 4; ++mt)
#pragma unroll
      for (int nt = 0; nt < 2; ++nt) {
        acc[4 + mt][nt] = __builtin_amdgcn_mfma_f32_16x16x32_bf16(
            fa[mt][0], fb[0][nt][0], acc[4 + mt][nt], 0, 0, 0);
        acc[4 + mt][nt] = __builtin_amdgcn_mfma_f32_16x16x32_bf16(
            fa[mt][1], fb[0][nt][1], acc[4 + mt][nt], 0, 0, 0);
      }
    __builtin_amdgcn_s_setprio(0);
    __builtin_amdgcn_s_barrier();
    // ---------------- phase 3: quad(m-half1, n-half1) ----------------
    if (p2) {
      gl_lds16(aS + 64LL * K + (kt + 128), dstA + bo + 8192);
      gl_lds16(bS + 64LL * K + (kt + 128), dstB + bo + 8192);
    }
    __builtin_amdgcn_s_barrier();
    __builtin_amdgcn_s_setprio(1);
#pragma unroll
    for (int mt = 0; mt < 4; ++mt)
#pragma unroll
      for (int nt = 0; nt < 2; ++nt) {
        acc[4 + mt][2 + nt] = __builtin_amdgcn_mfma_f32_16x16x32_bf16(
            fa[mt][0], fb[1][nt][0], acc[4 + mt][2 + nt], 0, 0, 0);
        acc[4 + mt][2 + nt] = __builtin_amdgcn_mfma_f32_16x16x32_bf16(
            fa[mt][1], fb[1][nt][1], acc[4 + mt][2 + nt], 0, 0, 0);
      }
    __builtin_amdgcn_s_setprio(0);
    // Counted wait. Loads still allowed in flight = ONLY the p2 loads
    // (tile+2 chunks 0,1 = 4 loads). When p2 is false (pipeline tail),
    // everything issued so far — including this tile's p1 loads, which the
    // NEXT tile reads — must drain: vmcnt(0). (Round-3 bug: unconditional
    // vmcnt(4) left the final tile's chunks 2,3 in flight -> stale reads.)
    if (p2) {
      asm volatile("s_waitcnt vmcnt(4)" ::: "memory");
    } else {
      asm volatile("s_waitcnt vmcnt(0)" ::: "memory");
    }
    __builtin_amdgcn_s_barrier();
  };

  for (int kt = 0; kt < K; kt += 128) {  // K % 128 == 0 for all launches
    tile(kt, 0, 32768);
    tile(kt + 64, 32768, 0);
  }

  // ---- epilogue; C/D layout: col = lane&15, row = q*4 + reg ----
#pragma unroll
  for (int ni = 0; ni < 4; ++ni) {
    const int col = n0 + wx * 64 + ni * 16 + lm;
    const float bvv = bias ? bias[col] : 0.0f;
#pragma unroll
    for (int mi = 0; mi < 8; ++mi) {
      const int rbase = m0 + wy * 128 + mi * 16 + q * 4;
      if constexpr (EPI == 3) {
        const int b = rbase / Mt;
        const int kk = rbase - b * Mt;
        unsigned short* dd =
            (unsigned short*)Cp + (long long)b * sC + (long long)col * Mt + kk;
        ushort4 pk;
        pk.x = f2bf(acc[mi][ni][0] * alpha + bvv);
        pk.y = f2bf(acc[mi][ni][1] * alpha + bvv);
        pk.z = f2bf(acc[mi][ni][2] * alpha + bvv);
        pk.w = f2bf(acc[mi][ni][3] * alpha + bvv);
        *reinterpret_cast<ushort4*>(dd) = pk;
      } else {
#pragma unroll
        for (int i = 0; i < 4; ++i) {
          const long long idx = zb * sC + (long long)(rbase + i) * N + col;
          const float x = acc[mi][ni][i] * alpha + bvv;
          if constexpr (EPI == 1) {
            ((unsigned short*)Cp)[idx] = f2bf(x);
          } else {  // EPI == 4: split h+l
            const unsigned short h = f2bf(x);
            ((unsigned short*)Cp)[idx] = h;
            Cl[idx] = f2bf(x - bf2f(h));
          }
        }
      }
    }
  }
}

// ===========================================================================
// Legacy 128² kernel — kept ONLY for the split-bf16 3-product out-projection.
// ===========================================================================
#define BM 128
#define BN 128
#define BK 32

template <int AMODE, bool BSPL, int EPI>
__global__ __launch_bounds__(256) void gemm_nt(
    const void* __restrict__ Apv, const unsigned short* __restrict__ Alp,
    const unsigned short* __restrict__ Bhp,
    const unsigned short* __restrict__ Blp, void* __restrict__ Cp,
    unsigned short* __restrict__ Cl, const float* __restrict__ bias,
    float alpha, int M, int N, int K, int Mt, long long sA, long long sB,
    long long sC) {
  __shared__ unsigned short As_h[BM * BK];
  __shared__ unsigned short Bs_h[BN * BK];
  __shared__ unsigned short As_l[(AMODE == 2) ? BM * BK : 8];
  __shared__ unsigned short Bs_l[BSPL ? BN * BK : 8];

  const int t = threadIdx.x;
  const int lane = t & 63;
  const int wave = t >> 6;
  const int wy = wave >> 1, wx = wave & 1;
  const int lm = lane & 15, q = lane >> 4;
  const int m0 = blockIdx.y * BM, n0 = blockIdx.x * BN;
  const long long zb = blockIdx.z;

  const unsigned short* Ahg = (const unsigned short*)Apv + zb * sA;
  const unsigned short* Alg = (AMODE == 2) ? (Alp + zb * sA) : nullptr;
  const unsigned short* Bhg = Bhp + zb * sB;
  const unsigned short* Blg = BSPL ? (Blp + zb * sB) : nullptr;

  floatx4 acc[4][4];
#pragma unroll
  for (int i = 0; i < 4; ++i)
#pragma unroll
    for (int j = 0; j < 4; ++j) acc[i][j] = (floatx4)(0.0f);

  const int ch_row = lane >> 2;
  const int ch_off = (lane & 3) << 3;

  for (int k0 = 0; k0 < K; k0 += BK) {
    __syncthreads();
#pragma unroll
    for (int j = 0; j < 2; ++j) {
      const int chunk = wave * 2 + j;
      const int row = chunk * 16 + ch_row;
      gl_lds16(Ahg + (long long)(m0 + row) * K + k0 + ch_off,
               &As_h[chunk * 512 + lane * 8]);
      if constexpr (AMODE == 2)
        gl_lds16(Alg + (long long)(m0 + row) * K + k0 + ch_off,
                 &As_l[chunk * 512 + lane * 8]);
    }
#pragma unroll
    for (int j = 0; j < 2; ++j) {
      const int chunk = wave * 2 + j;
      const int row = chunk * 16 + ch_row;
      gl_lds16(Bhg + (long long)(n0 + row) * K + k0 + ch_off,
               &Bs_h[chunk * 512 + lane * 8]);
      if constexpr (BSPL)
        gl_lds16(Blg + (long long)(n0 + row) * K + k0 + ch_off,
                 &Bs_l[chunk * 512 + lane * 8]);
    }
    __syncthreads();

    short8 fa[4], fb[4], fal[4], fbl[4];
#pragma unroll
    for (int mt = 0; mt < 4; ++mt) {
      const int row = wy * 64 + mt * 16 + lm;
      fa[mt] = *reinterpret_cast<const short8*>(&As_h[row * BK + q * 8]);
      if constexpr (AMODE == 2)
        fal[mt] = *reinterpret_cast<const short8*>(&As_l[row * BK + q * 8]);
    }
#pragma unroll
    for (int nt = 0; nt < 4; ++nt) {
      const int row = wx * 64 + nt * 16 + lm;
      fb[nt] = *reinterpret_cast<const short8*>(&Bs_h[row * BK + q * 8]);
      if constexpr (BSPL)
        fbl[nt] = *reinterpret_cast<const short8*>(&Bs_l[row * BK + q * 8]);
    }

#pragma unroll
    for (int mt = 0; mt < 4; ++mt)
#pragma unroll
      for (int nt = 0; nt < 4; ++nt) {
        acc[mt][nt] = __builtin_amdgcn_mfma_f32_16x16x32_bf16(
            fa[mt], fb[nt], acc[mt][nt], 0, 0, 0);
        if constexpr (AMODE == 2 && BSPL) {
          acc[mt][nt] = __builtin_amdgcn_mfma_f32_16x16x32_bf16(
              fa[mt], fbl[nt], acc[mt][nt], 0, 0, 0);
          acc[mt][nt] = __builtin_amdgcn_mfma_f32_16x16x32_bf16(
              fal[mt], fb[nt], acc[mt][nt], 0, 0, 0);
        }
      }
  }

#pragma unroll
  for (int nt = 0; nt < 4; ++nt) {
    const int col = n0 + wx * 64 + nt * 16 + lm;
    const float bv = bias ? bias[col] : 0.0f;
#pragma unroll
    for (int mt = 0; mt < 4; ++mt) {
      const int rbase = m0 + wy * 64 + mt * 16 + q * 4;
#pragma unroll
      for (int i = 0; i < 4; ++i) {
        const long long idx = zb * sC + (long long)(rbase + i) * N + col;
        const float x = acc[mt][nt][i] * alpha + bv;
        if constexpr (EPI == 0) {
          ((float*)Cp)[idx] = x;
        } else {
          ((unsigned short*)Cp)[idx] = f2bf(x);
        }
      }
    }
  }
}

// ---------------------------------------------------------------------------
// fp32 -> bf16 bulk convert (query / key_value), 8 elems/thread.
// ---------------------------------------------------------------------------
__global__ __launch_bounds__(256) void cvt_bf16(const float* __restrict__ in,
                                                unsigned short* __restrict__ o,
                                                int n8) {
  const int i = blockIdx.x * 256 + threadIdx.x;
  if (i >= n8) return;
  const float4* p = reinterpret_cast<const float4*>(in) + (long long)i * 2;
  const float4 a = p[0], b = p[1];
  short8 h;
  h[0] = (short)f2bf(a.x); h[1] = (short)f2bf(a.y);
  h[2] = (short)f2bf(a.z); h[3] = (short)f2bf(a.w);
  h[4] = (short)f2bf(b.x); h[5] = (short)f2bf(b.y);
  h[6] = (short)f2bf(b.z); h[7] = (short)f2bf(b.w);
  reinterpret_cast<short8*>(o)[i] = h;
}

// ---------------------------------------------------------------------------
// Weight prep: T = W^T as bf16-hi (and optional lo). W is (R,C) fp32.
// ---------------------------------------------------------------------------
__global__ __launch_bounds__(256) void prep_w(const float* __restrict__ W,
                                              unsigned short* __restrict__ Th,
                                              unsigned short* __restrict__ Tl,
                                              int R, int C) {
  __shared__ float tile[32][33];
  const int c0 = blockIdx.x * 32, r0 = blockIdx.y * 32;
  const int tx = threadIdx.x & 31, ty = threadIdx.x >> 5;
#pragma unroll
  for (int i = 0; i < 4; ++i)
    tile[ty + i * 8][tx] = W[(long long)(r0 + ty + i * 8) * C + c0 + tx];
  __syncthreads();
#pragma unroll
  for (int i = 0; i < 4; ++i) {
    const float x = tile[tx][ty + i * 8];
    const long long idx = (long long)(c0 + ty + i * 8) * R + r0 + tx;
    const unsigned short h = f2bf(x);
    Th[idx] = h;
    if (Tl) Tl[idx] = f2bf(x - bf2f(h));
  }
}

// ---------------------------------------------------------------------------
// Softmax: reads bf16 scores, int mask; writes fp32 attn (d_out) + bf16 Ph.
// ---------------------------------------------------------------------------
__device__ __forceinline__ float wave_max64(float v) {
#pragma unroll
  for (int o = 32; o > 0; o >>= 1) v = fmaxf(v, __shfl_xor(v, o, 64));
  return v;
}
__device__ __forceinline__ float wave_sum64(float v) {
#pragma unroll
  for (int o = 32; o > 0; o >>= 1) v += __shfl_xor(v, o, 64);
  return v;
}

__global__ __launch_bounds__(256) void softmax_kernel(
    const unsigned short* __restrict__ Sh, const int* __restrict__ mask,
    float* __restrict__ attn, unsigned short* __restrict__ Ph) {
  const long long base = (long long)blockIdx.x * 2048;
  const int t = threadIdx.x;

  float vals[8];
  float lmax = -INFINITY;
#pragma unroll
  for (int g = 0; g < 2; ++g) {
    const int idx = (t + g * 256) * 4;
    const uint2 u = *reinterpret_cast<const uint2*>(Sh + base + idx);
    const int4 m = *reinterpret_cast<const int4*>(mask + base + idx);
    vals[g * 4 + 0] = m.x ? bf2f((unsigned short)(u.x & 0xffff)) : -INFINITY;
    vals[g * 4 + 1] = m.y ? bf2f((unsigned short)(u.x >> 16)) : -INFINITY;
    vals[g * 4 + 2] = m.z ? bf2f((unsigned short)(u.y & 0xffff)) : -INFINITY;
    vals[g * 4 + 3] = m.w ? bf2f((unsigned short)(u.y >> 16)) : -INFINITY;
  }
#pragma unroll
  for (int i = 0; i < 8; ++i) lmax = fmaxf(lmax, vals[i]);

  __shared__ float red[4];
  const float wm = wave_max64(lmax);
  if ((t & 63) == 0) red[t >> 6] = wm;
  __syncthreads();
  const float rmax = fmaxf(fmaxf(red[0], red[1]), fmaxf(red[2], red[3]));
  __syncthreads();

  float lsum = 0.0f;
#pragma unroll
  for (int i = 0; i < 8; ++i) {
    const float e = __expf(vals[i] - rmax);
    vals[i] = e;
    lsum += e;
  }
  const float wsum = wave_sum64(lsum);
  if ((t & 63) == 0) red[t >> 6] = wsum;
  __syncthreads();
  const float inv = 1.0f / (red[0] + red[1] + red[2] + red[3]);

#pragma unroll
  for (int g = 0; g < 2; ++g) {
    const int idx = (t + g * 256) * 4;
    float4 o;
    o.x = vals[g * 4 + 0] * inv;
    o.y = vals[g * 4 + 1] * inv;
    o.z = vals[g * 4 + 2] * inv;
    o.w = vals[g * 4 + 3] * inv;
    *reinterpret_cast<float4*>(attn + base + idx) = o;
    uint2 p;
    p.x = (unsigned)f2bf(o.x) | ((unsigned)f2bf(o.y) << 16);
    p.y = (unsigned)f2bf(o.z) | ((unsigned)f2bf(o.w) << 16);
    *reinterpret_cast<uint2*>(Ph + base + idx) = p;
  }
}

// ---------------------------------------------------------------------------
extern "C" void kernel_launch(void* const* d_in, const int* in_sizes, int n_in,
                              void* d_out, int out_size, void* d_ws,
                              size_t ws_size, hipStream_t stream) {
  const float* query = (const float*)d_in[0];
  const float* keyv = (const float*)d_in[1];
  const int* mask = (const int*)d_in[2];
  const float* Wq = (const float*)d_in[3];
  const float* bq = (const float*)d_in[4];
  const float* Wk = (const float*)d_in[5];
  const float* bk = (const float*)d_in[6];
  const float* Wv = (const float*)d_in[7];
  const float* bv = (const float*)d_in[8];
  const float* Wo = (const float*)d_in[9];
  const float* bo = (const float*)d_in[10];

  const int B = 8, QL = 2048, KL = 2048, D = 1024;
  const long long ML = (long long)B * QL;  // 16384

  static int inited = 0;
  if (!inited) {
    hipFuncSetAttribute(reinterpret_cast<const void*>(&gemm8<1>),
                        hipFuncAttributeMaxDynamicSharedMemorySize, 131072);
    hipFuncSetAttribute(reinterpret_cast<const void*>(&gemm8<3>),
                        hipFuncAttributeMaxDynamicSharedMemorySize, 131072);
    hipFuncSetAttribute(reinterpret_cast<const void*>(&gemm8<4>),
                        hipFuncAttributeMaxDynamicSharedMemorySize, 131072);
    inited = 1;
  }

  float* out = (float*)d_out;      // (B,QL,D) fp32
  float* attn = out + ML * D;      // (B,QL,KL) fp32 — output 1

  // ws layout (170 MB total):
  //   [0,32)   Qh        — overlaid by Ph[0,64) after scores
  //   [32,64)  Kh
  //   [64,96)  VTh (B,D,KL)
  //   [96,160) Qf[96,128)+KVf[128,160) (bf16 activations, dead after V-proj)
  //            — then Sh (bf16 scores) — then Atth[96,128)+Attl[128,160)
  //   [160,170) WqT|WkT|WvT|WoTh|WoTl (2 MB each)
  char* w = (char*)d_ws;
  unsigned short* Qh = (unsigned short*)(w);
  unsigned short* Kh = (unsigned short*)(w + (32ll << 20));
  unsigned short* VTh = (unsigned short*)(w + (64ll << 20));
  unsigned short* Qf = (unsigned short*)(w + (96ll << 20));
  unsigned short* KVf = (unsigned short*)(w + (128ll << 20));
  unsigned short* Sh = (unsigned short*)(w + (96ll << 20));
  unsigned short* Ph = (unsigned short*)(w);
  unsigned short* Atth = (unsigned short*)(w + (96ll << 20));
  unsigned short* Attl = (unsigned short*)(w + (128ll << 20));
  unsigned short* WqT = (unsigned short*)(w + (160ll << 20));
  unsigned short* WkT = WqT + (1ll << 20);
  unsigned short* WvT = WkT + (1ll << 20);
  unsigned short* WoTh = WvT + (1ll << 20);
  unsigned short* WoTl = WoTh + (1ll << 20);

  const dim3 blk(256);
  const int n8 = (int)(ML * D / 8);  // 2097152

  cvt_bf16<<<dim3(n8 / 256), blk, 0, stream>>>(query, Qf, n8);
  cvt_bf16<<<dim3(n8 / 256), blk, 0, stream>>>(keyv, KVf, n8);

  prep_w<<<dim3(32, 32), blk, 0, stream>>>(Wq, WqT, nullptr, D, D);
  prep_w<<<dim3(32, 32), blk, 0, stream>>>(Wk, WkT, nullptr, D, D);
  prep_w<<<dim3(32, 32), blk, 0, stream>>>(Wv, WvT, nullptr, D, D);
  prep_w<<<dim3(32, 32), blk, 0, stream>>>(Wo, WoTh, WoTl, D, D);

  // Q/K projections -> bf16-hi, row-major
  gemm8<1><<<dim3(D / 256, ML / 256, 1), 512, 131072, stream>>>(
      Qf, WqT, Qh, nullptr, bq, 1.0f, (int)ML, D, D, 1, 0, 0, 0);
  gemm8<1><<<dim3(D / 256, ML / 256, 1), 512, 131072, stream>>>(
      KVf, WkT, Kh, nullptr, bk, 1.0f, (int)ML, D, D, 1, 0, 0, 0);
  // V projection -> bf16-hi, transposed per batch: VT (B, D, KL)
  gemm8<3><<<dim3(D / 256, ML / 256, 1), 512, 131072, stream>>>(
      KVf, WvT, VTh, nullptr, bv, 1.0f, (int)ML, D, D, KL, 0, 0,
      (long long)D * KL);

  // Scores: per-batch Qh . Kh^T / 32 -> Sh (bf16)
  gemm8<1><<<dim3(KL / 256, QL / 256, B), 512, 131072, stream>>>(
      Qh, Kh, Sh, nullptr, nullptr, 0.03125f, QL, KL, D, 1,
      (long long)QL * D, (long long)KL * D, (long long)QL * KL);

  // Softmax: Sh -> attn (fp32, d_out) + Ph (bf16)
  softmax_kernel<<<dim3((int)ML), blk, 0, stream>>>(Sh, mask, attn, Ph);

  // Attended: per-batch Ph . VT^T -> Att split (h+l)
  gemm8<4><<<dim3(D / 256, QL / 256, B), 512, 131072, stream>>>(
      Ph, VTh, Atth, Attl, nullptr, 1.0f, QL, D, KL, 1, (long long)QL * KL,
      (long long)D * KL, (long long)QL * D);

  // Output projection: Att(split) . WoT(split), 3-product -> d_out fp32
  gemm_nt<2, true, 0><<<dim3(D / BN, (int)ML / BM, 1), blk, 0, stream>>>(
      Atth, Attl, WoTh, WoTl, out, nullptr, bo, 1.0f, (int)ML, D, D, 1, 0, 0,
      0);
}

// Round 3
// 728.093 us; speedup vs baseline: 1.4194x; 1.1342x over previous
//
#include <hip/hip_runtime.h>
#include <hip/hip_bf16.h>
#include <math.h>

// ---------------------------------------------------------------------------
// Round 5: algebraic refactor — out = P·(V·Wo) instead of (P·V)·Wo.
//   Errors upstream of the P-contraction are damped by sqrt(sum p^2) ~ 1/45
//   (P rows sum to 1), so NO split-bf16 products are needed anywhere.
//   Fold further: V·Wo = kv·(Wv·Wo) + bv·Wo  ->  precompute W2T = (Wv·Wo)^T
//   (tiny 1024^3 GEMM) and bvWo = bv·Wo (micro-kernel); then
//     VWoT = kv·W2T + bvWo   (EPI=3 per-batch transpose, like old V-proj)
//     out  = Ph·VWoT + bo    (EPI=0 fp32 direct to d_out)
//   Deletes: V-proj, 3-product out-proj, legacy gemm_nt, Att h/l traffic.
//   gemm8 pipeline is byte-identical to round 4 (incl. tail vmcnt fix);
//   only a trivial EPI==0 epilogue branch is added.
// ---------------------------------------------------------------------------

typedef __attribute__((ext_vector_type(8))) short short8;   // 8 bf16
typedef __attribute__((ext_vector_type(4))) float floatx4;  // MFMA acc

__device__ __forceinline__ unsigned short f2bf(float x) {
  return __builtin_bit_cast(unsigned short, __float2bfloat16(x));
}
__device__ __forceinline__ float bf2f(unsigned short s) {
  unsigned int u = ((unsigned int)s) << 16;
  return __builtin_bit_cast(float, u);
}

typedef const unsigned int __attribute__((address_space(1))) ga_u32;
typedef unsigned int __attribute__((address_space(3))) lds_u32;
__device__ __forceinline__ void gl_lds16(const void* g, void* l) {
  __builtin_amdgcn_global_load_lds((ga_u32*)g, (lds_u32*)l, 16, 0, 0);
}

// ===========================================================================
// gemm8: C = A(MxK) . B(NxK)^T, bf16 inputs, 256x256 tile, BK=64, 512 thr.
//   8 waves (2 M x 4 N), wave tile 128x64, acc[8][4] of 16x16 frags.
//   LDS 128KB dynamic, XOR-swizzled via pre-swizzled global source.
//   4 phases per K-tile, counted vmcnt (p2 ? 4 : 0 — tail-safe), setprio,
//   XCD-contiguous block swizzle.
// EPI: 0 = fp32 out (+bias)                        [attended -> d_out]
//      1 = bf16 out (alpha, opt bias)              [Q/K proj, scores, W2T]
//      3 = bf16 out transposed per batch (+bias)   [VWo projection]
// ===========================================================================
template <int EPI>
__global__ __launch_bounds__(512, 2) void gemm8(
    const unsigned short* __restrict__ Ah,
    const unsigned short* __restrict__ Bh, void* __restrict__ Cp,
    const float* __restrict__ bias, float alpha, int M, int N, int K, int Mt,
    long long sA, long long sB, long long sC) {
  extern __shared__ char smem[];

  // ---- XCD-contiguous block swizzle (all launches have nwg % 8 == 0) ----
  const int gx = gridDim.x;
  const int gxy = gx * gridDim.y;
  const int nwg = gxy * gridDim.z;
  const int orig = blockIdx.z * gxy + blockIdx.y * gx + blockIdx.x;
  const int wg = (orig & 7) * (nwg >> 3) + (orig >> 3);
  const int zb_i = wg / gxy;
  const int rem = wg - zb_i * gxy;
  const int by = rem / gx;
  const int bx = rem - by * gx;
  const int m0 = by * 256, n0 = bx * 256;
  const long long zb = zb_i;

  const unsigned short* Ag = Ah + zb * sA;
  const unsigned short* Bg = Bh + zb * sB;

  const int t = threadIdx.x;
  // ---- staging: thread t loads 16B; LDS dest linear (chunk*8192 + t*16),
  //      global source carries the inverse swizzle ----
  const int srow = t >> 3;                              // row within 64-row chunk
  const int skw = ((t & 7) << 3) ^ ((srow & 7) << 3);   // swizzled k element
  const unsigned short* aS = Ag + (long long)(m0 + srow) * K + skw;
  const unsigned short* bS = Bg + (long long)(n0 + srow) * K + skw;
  char* dstA = smem + t * 16;
  char* dstB = smem + 65536 + t * 16;

  // ---- fragment-read bases (swizzled) ----
  const int lane = t & 63;
  const int wv = t >> 6, wy = wv >> 2, wx = wv & 3;  // 2 x 4 waves
  const int lm = lane & 15, q = lane >> 4;
  const int x0 = (q << 4) ^ ((lm & 7) << 4);
  const int aB0 = (wy * 128 + lm) * 128;
  const int bB0 = 65536 + (wx * 64 + lm) * 128;
  const int aRd0 = aB0 + x0, aRd1 = aB0 + (x0 ^ 64);  // kh = 0 / 1
  const int bRd0 = bB0 + x0, bRd1 = bB0 + (x0 ^ 64);

  floatx4 acc[8][4];
#pragma unroll
  for (int i = 0; i < 8; ++i)
#pragma unroll
    for (int j = 0; j < 4; ++j) acc[i][j] = (floatx4)(0.0f);

  short8 fa[4][2];     // current m-half A frags [mt][kh]
  short8 fb[2][2][2];  // both n-halves B frags [nh][nt][kh]

  // ---- prologue: tile0 chunks 0..3, tile1 chunks 0,1 (12 loads) ----
#pragma unroll
  for (int c = 0; c < 4; ++c) {
    gl_lds16(aS + (long long)(c * 64) * K, dstA + c * 8192);
    gl_lds16(bS + (long long)(c * 64) * K, dstB + c * 8192);
  }
  gl_lds16(aS + 64, dstA + 32768);
  gl_lds16(bS + 64, dstB + 32768);
  gl_lds16(aS + 64LL * K + 64, dstA + 32768 + 8192);
  gl_lds16(bS + 64LL * K + 64, dstB + 32768 + 8192);
  asm volatile("s_waitcnt vmcnt(4)" ::: "memory");  // tile0 resident
  __builtin_amdgcn_s_barrier();

  auto tile = [&](int kt, int bo, int nbo) {
    const bool p1 = (kt + 64) < K;   // stage tile+1 chunks 2,3 (into nbo)
    const bool p2 = (kt + 128) < K;  // stage tile+2 chunks 0,1 (into bo)
    // ---------------- phase 0: quad(m-half0, n-half0) ----------------
#pragma unroll
    for (int mt = 0; mt < 4; ++mt) {
      fa[mt][0] = *(const short8*)(smem + (bo + aRd0 + mt * 2048));
      fa[mt][1] = *(const short8*)(smem + (bo + aRd1 + mt * 2048));
    }
#pragma unroll
    for (int nt = 0; nt < 2; ++nt) {
      fb[0][nt][0] = *(const short8*)(smem + (bo + bRd0 + nt * 2048));
      fb[0][nt][1] = *(const short8*)(smem + (bo + bRd1 + nt * 2048));
    }
    if (p1) {
      gl_lds16(aS + 128LL * K + (kt + 64), dstA + nbo + 16384);
      gl_lds16(bS + 128LL * K + (kt + 64), dstB + nbo + 16384);
    }
    __builtin_amdgcn_s_barrier();
    __builtin_amdgcn_s_setprio(1);
#pragma unroll
    for (int mt = 0; mt < 4; ++mt)
#pragma unroll
      for (int nt = 0; nt < 2; ++nt) {
        acc[mt][nt] = __builtin_amdgcn_mfma_f32_16x16x32_bf16(
            fa[mt][0], fb[0][nt][0], acc[mt][nt], 0, 0, 0);
        acc[mt][nt] = __builtin_amdgcn_mfma_f32_16x16x32_bf16(
            fa[mt][1], fb[0][nt][1], acc[mt][nt], 0, 0, 0);
      }
    __builtin_amdgcn_s_setprio(0);
    __builtin_amdgcn_s_barrier();
    // ---------------- phase 1: quad(m-half0, n-half1) ----------------
#pragma unroll
    for (int nt = 0; nt < 2; ++nt) {
      fb[1][nt][0] = *(const short8*)(smem + (bo + bRd0 + 4096 + nt * 2048));
      fb[1][nt][1] = *(const short8*)(smem + (bo + bRd1 + 4096 + nt * 2048));
    }
    if (p1) {
      gl_lds16(aS + 192LL * K + (kt + 64), dstA + nbo + 24576);
      gl_lds16(bS + 192LL * K + (kt + 64), dstB + nbo + 24576);
    }
    __builtin_amdgcn_s_barrier();
    __builtin_amdgcn_s_setprio(1);
#pragma unroll
    for (int mt = 0; mt < 4; ++mt)
#pragma unroll
      for (int nt = 0; nt < 2; ++nt) {
        acc[mt][2 + nt] = __builtin_amdgcn_mfma_f32_16x16x32_bf16(
            fa[mt][0], fb[1][nt][0], acc[mt][2 + nt], 0, 0, 0);
        acc[mt][2 + nt] = __builtin_amdgcn_mfma_f32_16x16x32_bf16(
            fa[mt][1], fb[1][nt][1], acc[mt][2 + nt], 0, 0, 0);
      }
    __builtin_amdgcn_s_setprio(0);
    __builtin_amdgcn_s_barrier();
    // ---------------- phase 2: quad(m-half1, n-half0) ----------------
#pragma unroll
    for (int mt = 0; mt < 4; ++mt) {
      fa[mt][0] = *(const short8*)(smem + (bo + aRd0 + 8192 + mt * 2048));
      fa[mt][1] = *(const short8*)(smem + (bo + aRd1 + 8192 + mt * 2048));
    }
    if (p2) {  // chunk0 of this buffer is dead (read only in phase 0/1)
      gl_lds16(aS + (kt + 128), dstA + bo);
      gl_lds16(bS + (kt + 128), dstB + bo);
    }
    __builtin_amdgcn_s_barrier();
    __builtin_amdgcn_s_setprio(1);
#pragma unroll
    for (int mt = 0; mt < 4; ++mt)
#pragma unroll
      for (int nt = 0; nt < 2; ++nt) {
        acc[4 + mt][nt] = __builtin_amdgcn_mfma_f32_16x16x32_bf16(
            fa[mt][0], fb[0][nt][0], acc[4 + mt][nt], 0, 0, 0);
        acc[4 + mt][nt] = __builtin_amdgcn_mfma_f32_16x16x32_bf16(
            fa[mt][1], fb[0][nt][1], acc[4 + mt][nt], 0, 0, 0);
      }
    __builtin_amdgcn_s_setprio(0);
    __builtin_amdgcn_s_barrier();
    // ---------------- phase 3: quad(m-half1, n-half1) ----------------
    if (p2) {
      gl_lds16(aS + 64LL * K + (kt + 128), dstA + bo + 8192);
      gl_lds16(bS + 64LL * K + (kt + 128), dstB + bo + 8192);
    }
    __builtin_amdgcn_s_barrier();
    __builtin_amdgcn_s_setprio(1);
#pragma unroll
    for (int mt = 0; mt < 4; ++mt)
#pragma unroll
      for (int nt = 0; nt < 2; ++nt) {
        acc[4 + mt][2 + nt] = __builtin_amdgcn_mfma_f32_16x16x32_bf16(
            fa[mt][0], fb[1][nt][0], acc[4 + mt][2 + nt], 0, 0, 0);
        acc[4 + mt][2 + nt] = __builtin_amdgcn_mfma_f32_16x16x32_bf16(
            fa[mt][1], fb[1][nt][1], acc[4 + mt][2 + nt], 0, 0, 0);
      }
    __builtin_amdgcn_s_setprio(0);
    // Counted wait: only the p2 loads (tile+2 chunks 0,1) may stay in
    // flight; at the pipeline tail (p2 false) drain everything (round-4 fix).
    if (p2) {
      asm volatile("s_waitcnt vmcnt(4)" ::: "memory");
    } else {
      asm volatile("s_waitcnt vmcnt(0)" ::: "memory");
    }
    __builtin_amdgcn_s_barrier();
  };

  for (int kt = 0; kt < K; kt += 128) {  // K % 128 == 0 for all launches
    tile(kt, 0, 32768);
    tile(kt + 64, 32768, 0);
  }

  // ---- epilogue; C/D layout: col = lane&15, row = q*4 + reg ----
#pragma unroll
  for (int ni = 0; ni < 4; ++ni) {
    const int col = n0 + wx * 64 + ni * 16 + lm;
    const float bvv = bias ? bias[col] : 0.0f;
#pragma unroll
    for (int mi = 0; mi < 8; ++mi) {
      const int rbase = m0 + wy * 128 + mi * 16 + q * 4;
      if constexpr (EPI == 3) {
        const int b = rbase / Mt;
        const int kk = rbase - b * Mt;
        unsigned short* dd =
            (unsigned short*)Cp + (long long)b * sC + (long long)col * Mt + kk;
        ushort4 pk;
        pk.x = f2bf(acc[mi][ni][0] * alpha + bvv);
        pk.y = f2bf(acc[mi][ni][1] * alpha + bvv);
        pk.z = f2bf(acc[mi][ni][2] * alpha + bvv);
        pk.w = f2bf(acc[mi][ni][3] * alpha + bvv);
        *reinterpret_cast<ushort4*>(dd) = pk;
      } else {
#pragma unroll
        for (int i = 0; i < 4; ++i) {
          const long long idx = zb * sC + (long long)(rbase + i) * N + col;
          const float x = acc[mi][ni][i] * alpha + bvv;
          if constexpr (EPI == 0) {
            ((float*)Cp)[idx] = x;
          } else {  // EPI == 1
            ((unsigned short*)Cp)[idx] = f2bf(x);
          }
        }
      }
    }
  }
}

// ---------------------------------------------------------------------------
// fp32 -> bf16 bulk convert, 8 elems/thread.
// ---------------------------------------------------------------------------
__global__ __launch_bounds__(256) void cvt_bf16(const float* __restrict__ in,
                                                unsigned short* __restrict__ o,
                                                int n8) {
  const int i = blockIdx.x * 256 + threadIdx.x;
  if (i >= n8) return;
  const float4* p = reinterpret_cast<const float4*>(in) + (long long)i * 2;
  const float4 a = p[0], b = p[1];
  short8 h;
  h[0] = (short)f2bf(a.x); h[1] = (short)f2bf(a.y);
  h[2] = (short)f2bf(a.z); h[3] = (short)f2bf(a.w);
  h[4] = (short)f2bf(b.x); h[5] = (short)f2bf(b.y);
  h[6] = (short)f2bf(b.z); h[7] = (short)f2bf(b.w);
  reinterpret_cast<short8*>(o)[i] = h;
}

// ---------------------------------------------------------------------------
// Weight prep: T = W^T as bf16-hi. W is (R,C) fp32.
// ---------------------------------------------------------------------------
__global__ __launch_bounds__(256) void prep_w(const float* __restrict__ W,
                                              unsigned short* __restrict__ Th,
                                              int R, int C) {
  __shared__ float tile[32][33];
  const int c0 = blockIdx.x * 32, r0 = blockIdx.y * 32;
  const int tx = threadIdx.x & 31, ty = threadIdx.x >> 5;
#pragma unroll
  for (int i = 0; i < 4; ++i)
    tile[ty + i * 8][tx] = W[(long long)(r0 + ty + i * 8) * C + c0 + tx];
  __syncthreads();
#pragma unroll
  for (int i = 0; i < 4; ++i) {
    const float x = tile[tx][ty + i * 8];
    const long long idx = (long long)(c0 + ty + i * 8) * R + r0 + tx;
    Th[idx] = f2bf(x);
  }
}

// ---------------------------------------------------------------------------
// bvWo[f] = sum_e bv[e] * Wo[e][f]   (E = F = 1024). Grid 16, block 256.
// ---------------------------------------------------------------------------
__global__ __launch_bounds__(256) void bias_wo(const float* __restrict__ bv,
                                               const float* __restrict__ Wo,
                                               float* __restrict__ bvWo) {
  __shared__ float red[4][64];
  const int fl = threadIdx.x & 63, eg = threadIdx.x >> 6;
  const int f = blockIdx.x * 64 + fl;
  float s = 0.0f;
  const int e0 = eg * 256;
  for (int e = e0; e < e0 + 256; ++e)
    s += bv[e] * Wo[(long long)e * 1024 + f];
  red[eg][fl] = s;
  __syncthreads();
  if (eg == 0) bvWo[f] = red[0][fl] + red[1][fl] + red[2][fl] + red[3][fl];
}

// ---------------------------------------------------------------------------
// Softmax: reads bf16 scores, int mask; writes fp32 attn (d_out) + bf16 Ph.
// ---------------------------------------------------------------------------
__device__ __forceinline__ float wave_max64(float v) {
#pragma unroll
  for (int o = 32; o > 0; o >>= 1) v = fmaxf(v, __shfl_xor(v, o, 64));
  return v;
}
__device__ __forceinline__ float wave_sum64(float v) {
#pragma unroll
  for (int o = 32; o > 0; o >>= 1) v += __shfl_xor(v, o, 64);
  return v;
}

__global__ __launch_bounds__(256) void softmax_kernel(
    const unsigned short* __restrict__ Sh, const int* __restrict__ mask,
    float* __restrict__ attn, unsigned short* __restrict__ Ph) {
  const long long base = (long long)blockIdx.x * 2048;
  const int t = threadIdx.x;

  float vals[8];
  float lmax = -INFINITY;
#pragma unroll
  for (int g = 0; g < 2; ++g) {
    const int idx = (t + g * 256) * 4;
    const uint2 u = *reinterpret_cast<const uint2*>(Sh + base + idx);
    const int4 m = *reinterpret_cast<const int4*>(mask + base + idx);
    vals[g * 4 + 0] = m.x ? bf2f((unsigned short)(u.x & 0xffff)) : -INFINITY;
    vals[g * 4 + 1] = m.y ? bf2f((unsigned short)(u.x >> 16)) : -INFINITY;
    vals[g * 4 + 2] = m.z ? bf2f((unsigned short)(u.y & 0xffff)) : -INFINITY;
    vals[g * 4 + 3] = m.w ? bf2f((unsigned short)(u.y >> 16)) : -INFINITY;
  }
#pragma unroll
  for (int i = 0; i < 8; ++i) lmax = fmaxf(lmax, vals[i]);

  __shared__ float red[4];
  const float wm = wave_max64(lmax);
  if ((t & 63) == 0) red[t >> 6] = wm;
  __syncthreads();
  const float rmax = fmaxf(fmaxf(red[0], red[1]), fmaxf(red[2], red[3]));
  __syncthreads();

  float lsum = 0.0f;
#pragma unroll
  for (int i = 0; i < 8; ++i) {
    const float e = __expf(vals[i] - rmax);
    vals[i] = e;
    lsum += e;
  }
  const float wsum = wave_sum64(lsum);
  if ((t & 63) == 0) red[t >> 6] = wsum;
  __syncthreads();
  const float inv = 1.0f / (red[0] + red[1] + red[2] + red[3]);

#pragma unroll
  for (int g = 0; g < 2; ++g) {
    const int idx = (t + g * 256) * 4;
    float4 o;
    o.x = vals[g * 4 + 0] * inv;
    o.y = vals[g * 4 + 1] * inv;
    o.z = vals[g * 4 + 2] * inv;
    o.w = vals[g * 4 + 3] * inv;
    *reinterpret_cast<float4*>(attn + base + idx) = o;
    uint2 p;
    p.x = (unsigned)f2bf(o.x) | ((unsigned)f2bf(o.y) << 16);
    p.y = (unsigned)f2bf(o.z) | ((unsigned)f2bf(o.w) << 16);
    *reinterpret_cast<uint2*>(Ph + base + idx) = p;
  }
}

// ---------------------------------------------------------------------------
extern "C" void kernel_launch(void* const* d_in, const int* in_sizes, int n_in,
                              void* d_out, int out_size, void* d_ws,
                              size_t ws_size, hipStream_t stream) {
  const float* query = (const float*)d_in[0];
  const float* keyv = (const float*)d_in[1];
  const int* mask = (const int*)d_in[2];
  const float* Wq = (const float*)d_in[3];
  const float* bq = (const float*)d_in[4];
  const float* Wk = (const float*)d_in[5];
  const float* bk = (const float*)d_in[6];
  const float* Wv = (const float*)d_in[7];
  const float* bv = (const float*)d_in[8];
  const float* Wo = (const float*)d_in[9];
  const float* bo = (const float*)d_in[10];

  const int B = 8, QL = 2048, KL = 2048, D = 1024;
  const long long ML = (long long)B * QL;  // 16384

  static int inited = 0;
  if (!inited) {
    hipFuncSetAttribute(reinterpret_cast<const void*>(&gemm8<0>),
                        hipFuncAttributeMaxDynamicSharedMemorySize, 131072);
    hipFuncSetAttribute(reinterpret_cast<const void*>(&gemm8<1>),
                        hipFuncAttributeMaxDynamicSharedMemorySize, 131072);
    hipFuncSetAttribute(reinterpret_cast<const void*>(&gemm8<3>),
                        hipFuncAttributeMaxDynamicSharedMemorySize, 131072);
    inited = 1;
  }

  float* out = (float*)d_out;      // (B,QL,D) fp32
  float* attn = out + ML * D;      // (B,QL,KL) fp32 — output 1

  // ws layout (<= 170 MiB, same footprint as round 2/4):
  //   [0,32)    Qh           — overlaid by Ph[0,64) after scores
  //   [32,64)   Kh
  //   [64,96)   KVf (bf16 kv) — dead after VWo-proj; overlaid by Sh[64,128)
  //   [96,128)  Qf (bf16 q)   — dead after Q-proj;   overlaid by Sh
  //   [128,160) VWoT (B, E, KL) bf16 — live through attended
  //   [160,170) WqT | WkT | WoTh | W2T | WvH  (2 MiB each)
  //   bvWo (4 KB fp32) lives in the attn region of d_out (written later).
  char* w = (char*)d_ws;
  unsigned short* Qh = (unsigned short*)(w);
  unsigned short* Kh = (unsigned short*)(w + (32ll << 20));
  unsigned short* KVf = (unsigned short*)(w + (64ll << 20));
  unsigned short* Qf = (unsigned short*)(w + (96ll << 20));
  unsigned short* VWoT = (unsigned short*)(w + (128ll << 20));
  unsigned short* Sh = (unsigned short*)(w + (64ll << 20));
  unsigned short* Ph = (unsigned short*)(w);
  unsigned short* WqT = (unsigned short*)(w + (160ll << 20));
  unsigned short* WkT = WqT + (1ll << 20);
  unsigned short* WoTh = WkT + (1ll << 20);
  unsigned short* W2T = WoTh + (1ll << 20);
  unsigned short* WvH = W2T + (1ll << 20);
  float* bvWo = attn;  // scratch: consumed before softmax overwrites attn

  const dim3 blk(256);
  const int n8 = (int)(ML * D / 8);  // 2097152

  // --- input converts ---
  cvt_bf16<<<dim3(n8 / 256), blk, 0, stream>>>(query, Qf, n8);
  cvt_bf16<<<dim3(n8 / 256), blk, 0, stream>>>(keyv, KVf, n8);
  cvt_bf16<<<dim3(512), blk, 0, stream>>>(Wv, WvH, D * D / 8);  // row-major

  // --- weight prep ---
  prep_w<<<dim3(32, 32), blk, 0, stream>>>(Wq, WqT, D, D);
  prep_w<<<dim3(32, 32), blk, 0, stream>>>(Wk, WkT, D, D);
  prep_w<<<dim3(32, 32), blk, 0, stream>>>(Wo, WoTh, D, D);

  // --- bvWo = bv . Wo ---
  bias_wo<<<dim3(16), blk, 0, stream>>>(bv, Wo, bvWo);

  // --- W2T[f][d] = sum_e WoT[f][e] * Wv[d][e]  ( = (Wv.Wo)^T ) ---
  gemm8<1><<<dim3(D / 256, D / 256, 1), 512, 131072, stream>>>(
      WoTh, WvH, W2T, nullptr, 1.0f, D, D, D, 1, 0, 0, 0);

  // --- Q/K projections -> bf16, row-major ---
  gemm8<1><<<dim3(D / 256, ML / 256, 1), 512, 131072, stream>>>(
      Qf, WqT, Qh, bq, 1.0f, (int)ML, D, D, 1, 0, 0, 0);
  gemm8<1><<<dim3(D / 256, ML / 256, 1), 512, 131072, stream>>>(
      KVf, WkT, Kh, bk, 1.0f, (int)ML, D, D, 1, 0, 0, 0);

  // --- VWo projection: kv . W2T + bvWo -> transposed per batch (B, E, KL) ---
  gemm8<3><<<dim3(D / 256, ML / 256, 1), 512, 131072, stream>>>(
      KVf, W2T, VWoT, bvWo, 1.0f, (int)ML, D, D, KL, 0, 0,
      (long long)D * KL);

  // --- Scores: per-batch Qh . Kh^T / 32 -> Sh (bf16) ---
  gemm8<1><<<dim3(KL / 256, QL / 256, B), 512, 131072, stream>>>(
      Qh, Kh, Sh, nullptr, 0.03125f, QL, KL, D, 1,
      (long long)QL * D, (long long)KL * D, (long long)QL * KL);

  // --- Softmax: Sh -> attn (fp32, d_out) + Ph (bf16) ---
  softmax_kernel<<<dim3((int)ML), blk, 0, stream>>>(Sh, mask, attn, Ph);

  // --- Out: per-batch Ph . VWoT^T + bo -> d_out fp32 ---
  gemm8<0><<<dim3(D / 256, QL / 256, B), 512, 131072, stream>>>(
      Ph, VWoT, out, bo, 1.0f, QL, D, KL, 1, (long long)QL * KL,
      (long long)D * KL, (long long)QL * D);
}

// Round 6
// 722.004 us; speedup vs baseline: 1.4314x; 1.0084x over previous
//
#include <hip/hip_runtime.h>
#include <hip/hip_bf16.h>
#include <math.h>

// ---------------------------------------------------------------------------
// Round 6 (second resubmit after infra timeouts): fold K-projection into the
// score GEMM via W3 = Wq·Wk^T.
//   softmax(scale·(q·Wq+bq)·(kv·Wk+bk)^T) == softmax(scale·q·W3·kv^T + c_j)
//   (row-constant terms q·Wq·bk and bq·bk drop; c[b,j] = scale·kv_j·(Wk·bq)).
//   Deletes: K-projection GEMM (34.4 GF) + Kh traffic.
//   Weight-fold GEMMs (W3T, W2T; 2.1 GF each) move to a 128²-tile kernel
//   (64 blocks) instead of the 16-block gemm8 grid (~55 µs -> ~11 µs each).
//   gemm8 pipeline byte-identical to round 5. Biases handled exactly.
// ---------------------------------------------------------------------------

typedef __attribute__((ext_vector_type(8))) short short8;   // 8 bf16
typedef __attribute__((ext_vector_type(4))) float floatx4;  // MFMA acc

__device__ __forceinline__ unsigned short f2bf(float x) {
  return __builtin_bit_cast(unsigned short, __float2bfloat16(x));
}
__device__ __forceinline__ float bf2f(unsigned short s) {
  unsigned int u = ((unsigned int)s) << 16;
  return __builtin_bit_cast(float, u);
}

typedef const unsigned int __attribute__((address_space(1))) ga_u32;
typedef unsigned int __attribute__((address_space(3))) lds_u32;
__device__ __forceinline__ void gl_lds16(const void* g, void* l) {
  __builtin_amdgcn_global_load_lds((ga_u32*)g, (lds_u32*)l, 16, 0, 0);
}

// ===========================================================================
// gemm8: C = A(MxK) . B(NxK)^T, bf16 inputs, 256x256 tile, BK=64, 512 thr.
//   8 waves (2 M x 4 N), wave tile 128x64, acc[8][4] of 16x16 frags.
//   LDS 128KB dynamic, XOR-swizzled via pre-swizzled global source.
//   4 phases per K-tile, counted vmcnt (p2 ? 4 : 0 — tail-safe), setprio,
//   XCD-contiguous block swizzle.
// EPI: 0 = fp32 out (+bias)                        [out -> d_out]
//      1 = bf16 out (alpha, opt bias)              [qW3, scores]
//      3 = bf16 out transposed per batch (+bias)   [VWo projection]
// ===========================================================================
template <int EPI>
__global__ __launch_bounds__(512, 2) void gemm8(
    const unsigned short* __restrict__ Ah,
    const unsigned short* __restrict__ Bh, void* __restrict__ Cp,
    const float* __restrict__ bias, float alpha, int M, int N, int K, int Mt,
    long long sA, long long sB, long long sC) {
  extern __shared__ char smem[];

  // ---- XCD-contiguous block swizzle (all launches have nwg % 8 == 0) ----
  const int gx = gridDim.x;
  const int gxy = gx * gridDim.y;
  const int nwg = gxy * gridDim.z;
  const int orig = blockIdx.z * gxy + blockIdx.y * gx + blockIdx.x;
  const int wg = (orig & 7) * (nwg >> 3) + (orig >> 3);
  const int zb_i = wg / gxy;
  const int rem = wg - zb_i * gxy;
  const int by = rem / gx;
  const int bx = rem - by * gx;
  const int m0 = by * 256, n0 = bx * 256;
  const long long zb = zb_i;

  const unsigned short* Ag = Ah + zb * sA;
  const unsigned short* Bg = Bh + zb * sB;

  const int t = threadIdx.x;
  // ---- staging: thread t loads 16B; LDS dest linear (chunk*8192 + t*16),
  //      global source carries the inverse swizzle ----
  const int srow = t >> 3;                              // row within 64-row chunk
  const int skw = ((t & 7) << 3) ^ ((srow & 7) << 3);   // swizzled k element
  const unsigned short* aS = Ag + (long long)(m0 + srow) * K + skw;
  const unsigned short* bS = Bg + (long long)(n0 + srow) * K + skw;
  char* dstA = smem + t * 16;
  char* dstB = smem + 65536 + t * 16;

  // ---- fragment-read bases (swizzled) ----
  const int lane = t & 63;
  const int wv = t >> 6, wy = wv >> 2, wx = wv & 3;  // 2 x 4 waves
  const int lm = lane & 15, q = lane >> 4;
  const int x0 = (q << 4) ^ ((lm & 7) << 4);
  const int aB0 = (wy * 128 + lm) * 128;
  const int bB0 = 65536 + (wx * 64 + lm) * 128;
  const int aRd0 = aB0 + x0, aRd1 = aB0 + (x0 ^ 64);  // kh = 0 / 1
  const int bRd0 = bB0 + x0, bRd1 = bB0 + (x0 ^ 64);

  floatx4 acc[8][4];
#pragma unroll
  for (int i = 0; i < 8; ++i)
#pragma unroll
    for (int j = 0; j < 4; ++j) acc[i][j] = (floatx4)(0.0f);

  short8 fa[4][2];     // current m-half A frags [mt][kh]
  short8 fb[2][2][2];  // both n-halves B frags [nh][nt][kh]

  // ---- prologue: tile0 chunks 0..3, tile1 chunks 0,1 (12 loads) ----
#pragma unroll
  for (int c = 0; c < 4; ++c) {
    gl_lds16(aS + (long long)(c * 64) * K, dstA + c * 8192);
    gl_lds16(bS + (long long)(c * 64) * K, dstB + c * 8192);
  }
  gl_lds16(aS + 64, dstA + 32768);
  gl_lds16(bS + 64, dstB + 32768);
  gl_lds16(aS + 64LL * K + 64, dstA + 32768 + 8192);
  gl_lds16(bS + 64LL * K + 64, dstB + 32768 + 8192);
  asm volatile("s_waitcnt vmcnt(4)" ::: "memory");  // tile0 resident
  __builtin_amdgcn_s_barrier();

  auto tile = [&](int kt, int bo, int nbo) {
    const bool p1 = (kt + 64) < K;   // stage tile+1 chunks 2,3 (into nbo)
    const bool p2 = (kt + 128) < K;  // stage tile+2 chunks 0,1 (into bo)
    // ---------------- phase 0: quad(m-half0, n-half0) ----------------
#pragma unroll
    for (int mt = 0; mt < 4; ++mt) {
      fa[mt][0] = *(const short8*)(smem + (bo + aRd0 + mt * 2048));
      fa[mt][1] = *(const short8*)(smem + (bo + aRd1 + mt * 2048));
    }
#pragma unroll
    for (int nt = 0; nt < 2; ++nt) {
      fb[0][nt][0] = *(const short8*)(smem + (bo + bRd0 + nt * 2048));
      fb[0][nt][1] = *(const short8*)(smem + (bo + bRd1 + nt * 2048));
    }
    if (p1) {
      gl_lds16(aS + 128LL * K + (kt + 64), dstA + nbo + 16384);
      gl_lds16(bS + 128LL * K + (kt + 64), dstB + nbo + 16384);
    }
    __builtin_amdgcn_s_barrier();
    __builtin_amdgcn_s_setprio(1);
#pragma unroll
    for (int mt = 0; mt < 4; ++mt)
#pragma unroll
      for (int nt = 0; nt < 2; ++nt) {
        acc[mt][nt] = __builtin_amdgcn_mfma_f32_16x16x32_bf16(
            fa[mt][0], fb[0][nt][0], acc[mt][nt], 0, 0, 0);
        acc[mt][nt] = __builtin_amdgcn_mfma_f32_16x16x32_bf16(
            fa[mt][1], fb[0][nt][1], acc[mt][nt], 0, 0, 0);
      }
    __builtin_amdgcn_s_setprio(0);
    __builtin_amdgcn_s_barrier();
    // ---------------- phase 1: quad(m-half0, n-half1) ----------------
#pragma unroll
    for (int nt = 0; nt < 2; ++nt) {
      fb[1][nt][0] = *(const short8*)(smem + (bo + bRd0 + 4096 + nt * 2048));
      fb[1][nt][1] = *(const short8*)(smem + (bo + bRd1 + 4096 + nt * 2048));
    }
    if (p1) {
      gl_lds16(aS + 192LL * K + (kt + 64), dstA + nbo + 24576);
      gl_lds16(bS + 192LL * K + (kt + 64), dstB + nbo + 24576);
    }
    __builtin_amdgcn_s_barrier();
    __builtin_amdgcn_s_setprio(1);
#pragma unroll
    for (int mt = 0; mt < 4; ++mt)
#pragma unroll
      for (int nt = 0; nt < 2; ++nt) {
        acc[mt][2 + nt] = __builtin_amdgcn_mfma_f32_16x16x32_bf16(
            fa[mt][0], fb[1][nt][0], acc[mt][2 + nt], 0, 0, 0);
        acc[mt][2 + nt] = __builtin_amdgcn_mfma_f32_16x16x32_bf16(
            fa[mt][1], fb[1][nt][1], acc[mt][2 + nt], 0, 0, 0);
      }
    __builtin_amdgcn_s_setprio(0);
    __builtin_amdgcn_s_barrier();
    // ---------------- phase 2: quad(m-half1, n-half0) ----------------
#pragma unroll
    for (int mt = 0; mt < 4; ++mt) {
      fa[mt][0] = *(const short8*)(smem + (bo + aRd0 + 8192 + mt * 2048));
      fa[mt][1] = *(const short8*)(smem + (bo + aRd1 + 8192 + mt * 2048));
    }
    if (p2) {  // chunk0 of this buffer is dead (read only in phase 0/1)
      gl_lds16(aS + (kt + 128), dstA + bo);
      gl_lds16(bS + (kt + 128), dstB + bo);
    }
    __builtin_amdgcn_s_barrier();
    __builtin_amdgcn_s_setprio(1);
#pragma unroll
    for (int mt = 0; mt < 4; ++mt)
#pragma unroll
      for (int nt = 0; nt < 2; ++nt) {
        acc[4 + mt][nt] = __builtin_amdgcn_mfma_f32_16x16x32_bf16(
            fa[mt][0], fb[0][nt][0], acc[4 + mt][nt], 0, 0, 0);
        acc[4 + mt][nt] = __builtin_amdgcn_mfma_f32_16x16x32_bf16(
            fa[mt][1], fb[0][nt][1], acc[4 + mt][nt], 0, 0, 0);
      }
    __builtin_amdgcn_s_setprio(0);
    __builtin_amdgcn_s_barrier();
    // ---------------- phase 3: quad(m-half1, n-half1) ----------------
    if (p2) {
      gl_lds16(aS + 64LL * K + (kt + 128), dstA + bo + 8192);
      gl_lds16(bS + 64LL * K + (kt + 128), dstB + bo + 8192);
    }
    __builtin_amdgcn_s_barrier();
    __builtin_amdgcn_s_setprio(1);
#pragma unroll
    for (int mt = 0; mt < 4; ++mt)
#pragma unroll
      for (int nt = 0; nt < 2; ++nt) {
        acc[4 + mt][2 + nt] = __builtin_amdgcn_mfma_f32_16x16x32_bf16(
            fa[mt][0], fb[1][nt][0], acc[4 + mt][2 + nt], 0, 0, 0);
        acc[4 + mt][2 + nt] = __builtin_amdgcn_mfma_f32_16x16x32_bf16(
            fa[mt][1], fb[1][nt][1], acc[4 + mt][2 + nt], 0, 0, 0);
      }
    __builtin_amdgcn_s_setprio(0);
    // Counted wait: only the p2 loads (tile+2 chunks 0,1) may stay in
    // flight; at the pipeline tail (p2 false) drain everything.
    if (p2) {
      asm volatile("s_waitcnt vmcnt(4)" ::: "memory");
    } else {
      asm volatile("s_waitcnt vmcnt(0)" ::: "memory");
    }
    __builtin_amdgcn_s_barrier();
  };

  for (int kt = 0; kt < K; kt += 128) {  // K % 128 == 0 for all launches
    tile(kt, 0, 32768);
    tile(kt + 64, 32768, 0);
  }

  // ---- epilogue; C/D layout: col = lane&15, row = q*4 + reg ----
#pragma unroll
  for (int ni = 0; ni < 4; ++ni) {
    const int col = n0 + wx * 64 + ni * 16 + lm;
    const float bvv = bias ? bias[col] : 0.0f;
#pragma unroll
    for (int mi = 0; mi < 8; ++mi) {
      const int rbase = m0 + wy * 128 + mi * 16 + q * 4;
      if constexpr (EPI == 3) {
        const int b = rbase / Mt;
        const int kk = rbase - b * Mt;
        unsigned short* dd =
            (unsigned short*)Cp + (long long)b * sC + (long long)col * Mt + kk;
        ushort4 pk;
        pk.x = f2bf(acc[mi][ni][0] * alpha + bvv);
        pk.y = f2bf(acc[mi][ni][1] * alpha + bvv);
        pk.z = f2bf(acc[mi][ni][2] * alpha + bvv);
        pk.w = f2bf(acc[mi][ni][3] * alpha + bvv);
        *reinterpret_cast<ushort4*>(dd) = pk;
      } else {
#pragma unroll
        for (int i = 0; i < 4; ++i) {
          const long long idx = zb * sC + (long long)(rbase + i) * N + col;
          const float x = acc[mi][ni][i] * alpha + bvv;
          if constexpr (EPI == 0) {
            ((float*)Cp)[idx] = x;
          } else {  // EPI == 1
            ((unsigned short*)Cp)[idx] = f2bf(x);
          }
        }
      }
    }
  }
}

// ===========================================================================
// gemm128: small single-product bf16 NT GEMM (128² tile, 256 thr) for the
// two 1024³ weight folds (W3T, W2T) — 64 blocks instead of gemm8's 16.
// C[m,n] = sum_k A[m,k]·B[n,k], bf16 out. (Proven round-0/2 structure.)
// ===========================================================================
__global__ __launch_bounds__(256) void gemm128(
    const unsigned short* __restrict__ A, const unsigned short* __restrict__ B,
    unsigned short* __restrict__ C, int M, int N, int K) {
  __shared__ unsigned short As_h[128 * 32];
  __shared__ unsigned short Bs_h[128 * 32];

  const int t = threadIdx.x;
  const int lane = t & 63;
  const int wave = t >> 6;
  const int wy = wave >> 1, wx = wave & 1;
  const int lm = lane & 15, q = lane >> 4;
  const int m0 = blockIdx.y * 128, n0 = blockIdx.x * 128;

  floatx4 acc[4][4];
#pragma unroll
  for (int i = 0; i < 4; ++i)
#pragma unroll
    for (int j = 0; j < 4; ++j) acc[i][j] = (floatx4)(0.0f);

  const int ch_row = lane >> 2;
  const int ch_off = (lane & 3) << 3;

  for (int k0 = 0; k0 < K; k0 += 32) {
    __syncthreads();
#pragma unroll
    for (int j = 0; j < 2; ++j) {
      const int chunk = wave * 2 + j;
      const int row = chunk * 16 + ch_row;
      gl_lds16(A + (long long)(m0 + row) * K + k0 + ch_off,
               &As_h[chunk * 512 + lane * 8]);
      gl_lds16(B + (long long)(n0 + row) * K + k0 + ch_off,
               &Bs_h[chunk * 512 + lane * 8]);
    }
    __syncthreads();

    short8 fa[4], fb[4];
#pragma unroll
    for (int mt = 0; mt < 4; ++mt) {
      const int row = wy * 64 + mt * 16 + lm;
      fa[mt] = *reinterpret_cast<const short8*>(&As_h[row * 32 + q * 8]);
    }
#pragma unroll
    for (int nt = 0; nt < 4; ++nt) {
      const int row = wx * 64 + nt * 16 + lm;
      fb[nt] = *reinterpret_cast<const short8*>(&Bs_h[row * 32 + q * 8]);
    }
#pragma unroll
    for (int mt = 0; mt < 4; ++mt)
#pragma unroll
      for (int nt = 0; nt < 4; ++nt)
        acc[mt][nt] = __builtin_amdgcn_mfma_f32_16x16x32_bf16(
            fa[mt], fb[nt], acc[mt][nt], 0, 0, 0);
  }

#pragma unroll
  for (int nt = 0; nt < 4; ++nt) {
    const int col = n0 + wx * 64 + nt * 16 + lm;
#pragma unroll
    for (int mt = 0; mt < 4; ++mt) {
      const int rbase = m0 + wy * 64 + mt * 16 + q * 4;
#pragma unroll
      for (int i = 0; i < 4; ++i)
        C[(long long)(rbase + i) * N + col] = f2bf(acc[mt][nt][i]);
    }
  }
}

// ---------------------------------------------------------------------------
// fp32 -> bf16 bulk convert, 8 elems/thread.
// ---------------------------------------------------------------------------
__global__ __launch_bounds__(256) void cvt_bf16(const float* __restrict__ in,
                                                unsigned short* __restrict__ o,
                                                int n8) {
  const int i = blockIdx.x * 256 + threadIdx.x;
  if (i >= n8) return;
  const float4* p = reinterpret_cast<const float4*>(in) + (long long)i * 2;
  const float4 a = p[0], b = p[1];
  short8 h;
  h[0] = (short)f2bf(a.x); h[1] = (short)f2bf(a.y);
  h[2] = (short)f2bf(a.z); h[3] = (short)f2bf(a.w);
  h[4] = (short)f2bf(b.x); h[5] = (short)f2bf(b.y);
  h[6] = (short)f2bf(b.z); h[7] = (short)f2bf(b.w);
  reinterpret_cast<short8*>(o)[i] = h;
}

// ---------------------------------------------------------------------------
// Weight prep: T = W^T as bf16. W is (R,C) fp32.
// ---------------------------------------------------------------------------
__global__ __launch_bounds__(256) void prep_w(const float* __restrict__ W,
                                              unsigned short* __restrict__ Th,
                                              int R, int C) {
  __shared__ float tile[32][33];
  const int c0 = blockIdx.x * 32, r0 = blockIdx.y * 32;
  const int tx = threadIdx.x & 31, ty = threadIdx.x >> 5;
#pragma unroll
  for (int i = 0; i < 4; ++i)
    tile[ty + i * 8][tx] = W[(long long)(r0 + ty + i * 8) * C + c0 + tx];
  __syncthreads();
#pragma unroll
  for (int i = 0; i < 4; ++i) {
    const float x = tile[tx][ty + i * 8];
    const long long idx = (long long)(c0 + ty + i * 8) * R + r0 + tx;
    Th[idx] = f2bf(x);
  }
}

__device__ __forceinline__ float wave_max64(float v) {
#pragma unroll
  for (int o = 32; o > 0; o >>= 1) v = fmaxf(v, __shfl_xor(v, o, 64));
  return v;
}
__device__ __forceinline__ float wave_sum64(float v) {
#pragma unroll
  for (int o = 32; o > 0; o >>= 1) v += __shfl_xor(v, o, 64);
  return v;
}

// ---------------------------------------------------------------------------
// bvWo[f] = sum_e bv[e] * Wo[e][f]   (E = F = 1024). Grid 16, block 256.
// ---------------------------------------------------------------------------
__global__ __launch_bounds__(256) void bias_wo(const float* __restrict__ bv,
                                               const float* __restrict__ Wo,
                                               float* __restrict__ bvWo) {
  __shared__ float red[4][64];
  const int fl = threadIdx.x & 63, eg = threadIdx.x >> 6;
  const int f = blockIdx.x * 64 + fl;
  float s = 0.0f;
  const int e0 = eg * 256;
  for (int e = e0; e < e0 + 256; ++e)
    s += bv[e] * Wo[(long long)e * 1024 + f];
  red[eg][fl] = s;
  __syncthreads();
  if (eg == 0) bvWo[f] = red[0][fl] + red[1][fl] + red[2][fl] + red[3][fl];
}

// ---------------------------------------------------------------------------
// w4[d] = sum_e Wk[d][e] * bq[e].  One wave per row; grid D/4, block 256.
// ---------------------------------------------------------------------------
__global__ __launch_bounds__(256) void wk_bq(const float* __restrict__ Wk,
                                             const float* __restrict__ bq,
                                             float* __restrict__ w4) {
  const int lane = threadIdx.x & 63, wv = threadIdx.x >> 6;
  const int d = blockIdx.x * 4 + wv;
  const float* row = Wk + (long long)d * 1024;
  float s = 0.0f;
#pragma unroll
  for (int i = 0; i < 16; ++i) s += row[lane + i * 64] * bq[lane + i * 64];
  s = wave_sum64(s);
  if (lane == 0) w4[d] = s;
}

// ---------------------------------------------------------------------------
// c[r] = scale * dot(KVf[r,:], w4)  for r in [0, B*KL). One wave per row.
// ---------------------------------------------------------------------------
__global__ __launch_bounds__(256) void kv_dot(
    const unsigned short* __restrict__ kvh, const float* __restrict__ w4,
    float scale, float* __restrict__ c) {
  const int lane = threadIdx.x & 63, wv = threadIdx.x >> 6;
  const long long r = (long long)blockIdx.x * 4 + wv;
  const unsigned short* p = kvh + r * 1024 + lane * 16;
  const short8 h0 = *(const short8*)(p);
  const short8 h1 = *(const short8*)(p + 8);
  float s = 0.0f;
#pragma unroll
  for (int i = 0; i < 8; ++i) s += bf2f((unsigned short)h0[i]) * w4[lane * 16 + i];
#pragma unroll
  for (int i = 0; i < 8; ++i) s += bf2f((unsigned short)h1[i]) * w4[lane * 16 + 8 + i];
  s = wave_sum64(s);
  if (lane == 0) c[r] = s * scale;
}

// ---------------------------------------------------------------------------
// Softmax: bf16 scores + per-column bias c + int mask ->
//          fp32 attn (d_out) + bf16 Ph.
// ---------------------------------------------------------------------------
__global__ __launch_bounds__(256) void softmax_kernel(
    const unsigned short* __restrict__ Sh, const int* __restrict__ mask,
    const float* __restrict__ c, float* __restrict__ attn,
    unsigned short* __restrict__ Ph) {
  const long long base = (long long)blockIdx.x * 2048;
  const long long cb = (long long)(blockIdx.x >> 11) * 2048;  // batch row of c
  const int t = threadIdx.x;

  float vals[8];
  float lmax = -INFINITY;
#pragma unroll
  for (int g = 0; g < 2; ++g) {
    const int idx = (t + g * 256) * 4;
    const uint2 u = *reinterpret_cast<const uint2*>(Sh + base + idx);
    const int4 m = *reinterpret_cast<const int4*>(mask + base + idx);
    const float4 cv = *reinterpret_cast<const float4*>(c + cb + idx);
    vals[g * 4 + 0] =
        m.x ? bf2f((unsigned short)(u.x & 0xffff)) + cv.x : -INFINITY;
    vals[g * 4 + 1] =
        m.y ? bf2f((unsigned short)(u.x >> 16)) + cv.y : -INFINITY;
    vals[g * 4 + 2] =
        m.z ? bf2f((unsigned short)(u.y & 0xffff)) + cv.z : -INFINITY;
    vals[g * 4 + 3] =
        m.w ? bf2f((unsigned short)(u.y >> 16)) + cv.w : -INFINITY;
  }
#pragma unroll
  for (int i = 0; i < 8; ++i) lmax = fmaxf(lmax, vals[i]);

  __shared__ float red[4];
  const float wm = wave_max64(lmax);
  if ((t & 63) == 0) red[t >> 6] = wm;
  __syncthreads();
  const float rmax = fmaxf(fmaxf(red[0], red[1]), fmaxf(red[2], red[3]));
  __syncthreads();

  float lsum = 0.0f;
#pragma unroll
  for (int i = 0; i < 8; ++i) {
    const float e = __expf(vals[i] - rmax);
    vals[i] = e;
    lsum += e;
  }
  const float wsum = wave_sum64(lsum);
  if ((t & 63) == 0) red[t >> 6] = wsum;
  __syncthreads();
  const float inv = 1.0f / (red[0] + red[1] + red[2] + red[3]);

#pragma unroll
  for (int g = 0; g < 2; ++g) {
    const int idx = (t + g * 256) * 4;
    float4 o;
    o.x = vals[g * 4 + 0] * inv;
    o.y = vals[g * 4 + 1] * inv;
    o.z = vals[g * 4 + 2] * inv;
    o.w = vals[g * 4 + 3] * inv;
    *reinterpret_cast<float4*>(attn + base + idx) = o;
    uint2 p;
    p.x = (unsigned)f2bf(o.x) | ((unsigned)f2bf(o.y) << 16);
    p.y = (unsigned)f2bf(o.z) | ((unsigned)f2bf(o.w) << 16);
    *reinterpret_cast<uint2*>(Ph + base + idx) = p;
  }
}

// ---------------------------------------------------------------------------
extern "C" void kernel_launch(void* const* d_in, const int* in_sizes, int n_in,
                              void* d_out, int out_size, void* d_ws,
                              size_t ws_size, hipStream_t stream) {
  const float* query = (const float*)d_in[0];
  const float* keyv = (const float*)d_in[1];
  const int* mask = (const int*)d_in[2];
  const float* Wq = (const float*)d_in[3];
  const float* bq = (const float*)d_in[4];
  const float* Wk = (const float*)d_in[5];
  const float* bk = (const float*)d_in[6];
  const float* Wv = (const float*)d_in[7];
  const float* bv = (const float*)d_in[8];
  const float* Wo = (const float*)d_in[9];
  const float* bo = (const float*)d_in[10];
  (void)bk;  // drops out of softmax (row-constant terms)

  const int B = 8, QL = 2048, KL = 2048, D = 1024;
  const long long ML = (long long)B * QL;  // 16384

  static int inited = 0;
  if (!inited) {
    hipFuncSetAttribute(reinterpret_cast<const void*>(&gemm8<0>),
                        hipFuncAttributeMaxDynamicSharedMemorySize, 131072);
    hipFuncSetAttribute(reinterpret_cast<const void*>(&gemm8<1>),
                        hipFuncAttributeMaxDynamicSharedMemorySize, 131072);
    hipFuncSetAttribute(reinterpret_cast<const void*>(&gemm8<3>),
                        hipFuncAttributeMaxDynamicSharedMemorySize, 131072);
    inited = 1;
  }

  float* out = (float*)d_out;      // (B,QL,D) fp32
  float* attn = out + ML * D;      // (B,QL,KL) fp32 — output 1

  // ws layout (<= 170 MiB):
  //   [0,32)    QW3h (bf16 q·W3) — overlaid by Ph[0,64) after scores
  //   [32,64)   KVf (bf16 kv)    — dead after scores; Ph overlays
  //   [64,128)  Sh (bf16 scores) — [96,128) transiently Qf (dead after qW3)
  //   [128,160) VWoT (B,E,KL)    — transiently WqH/WkH/WvH/WoTh @128/130/132/134
  //   [160,170) W2T@160 | W3T@162 | c@164 | w4@165 | bvWo@166
  char* w = (char*)d_ws;
  unsigned short* QW3h = (unsigned short*)(w);
  unsigned short* KVf = (unsigned short*)(w + (32ll << 20));
  unsigned short* Sh = (unsigned short*)(w + (64ll << 20));
  unsigned short* Qf = (unsigned short*)(w + (96ll << 20));
  unsigned short* VWoT = (unsigned short*)(w + (128ll << 20));
  unsigned short* Ph = (unsigned short*)(w);
  unsigned short* WqH = (unsigned short*)(w + (128ll << 20));
  unsigned short* WkH = (unsigned short*)(w + (130ll << 20));
  unsigned short* WvH = (unsigned short*)(w + (132ll << 20));
  unsigned short* WoTh = (unsigned short*)(w + (134ll << 20));
  unsigned short* W2T = (unsigned short*)(w + (160ll << 20));
  unsigned short* W3T = (unsigned short*)(w + (162ll << 20));
  float* cvec = (float*)(w + (164ll << 20));
  float* w4 = (float*)(w + (165ll << 20));
  float* bvWo = (float*)(w + (166ll << 20));

  const dim3 blk(256);
  const int n8 = (int)(ML * D / 8);  // 2097152

  // --- weight preps (transient buffers inside the VWoT slot) ---
  cvt_bf16<<<dim3(512), blk, 0, stream>>>(Wq, WqH, D * D / 8);
  cvt_bf16<<<dim3(512), blk, 0, stream>>>(Wk, WkH, D * D / 8);
  cvt_bf16<<<dim3(512), blk, 0, stream>>>(Wv, WvH, D * D / 8);
  prep_w<<<dim3(32, 32), blk, 0, stream>>>(Wo, WoTh, D, D);
  wk_bq<<<dim3(D / 4), blk, 0, stream>>>(Wk, bq, w4);
  bias_wo<<<dim3(16), blk, 0, stream>>>(bv, Wo, bvWo);

  // --- W3T[d'][d] = sum_e Wk[d',e]·Wq[d,e]  (B-operand of qW3 GEMM) ---
  gemm128<<<dim3(8, 8), blk, 0, stream>>>(WkH, WqH, W3T, D, D, D);
  // --- W2T[f][d]  = sum_e Wo[e,f]·Wv[d,e]   (B-operand of VWo GEMM) ---
  gemm128<<<dim3(8, 8), blk, 0, stream>>>(WoTh, WvH, W2T, D, D, D);

  // --- activation converts ---
  cvt_bf16<<<dim3(n8 / 256), blk, 0, stream>>>(query, Qf, n8);
  cvt_bf16<<<dim3(n8 / 256), blk, 0, stream>>>(keyv, KVf, n8);

  // --- c[b,j] = scale · kv[b,j]·w4  (column softmax bias; exact) ---
  kv_dot<<<dim3((int)ML / 4), blk, 0, stream>>>(KVf, w4, 0.03125f, cvec);

  // --- qW3 = q·W3 -> bf16 (replaces Q AND K projections) ---
  gemm8<1><<<dim3(D / 256, ML / 256, 1), 512, 131072, stream>>>(
      Qf, W3T, QW3h, nullptr, 1.0f, (int)ML, D, D, 1, 0, 0, 0);

  // --- VWo projection: kv·W2T + bvWo -> transposed per batch (B, E, KL) ---
  gemm8<3><<<dim3(D / 256, ML / 256, 1), 512, 131072, stream>>>(
      KVf, W2T, VWoT, bvWo, 1.0f, (int)ML, D, D, KL, 0, 0,
      (long long)D * KL);

  // --- Scores: per-batch (qW3)·kv^T · scale -> Sh (bf16) ---
  gemm8<1><<<dim3(KL / 256, QL / 256, B), 512, 131072, stream>>>(
      QW3h, KVf, Sh, nullptr, 0.03125f, QL, KL, D, 1,
      (long long)QL * D, (long long)KL * D, (long long)QL * KL);

  // --- Softmax(+c): Sh -> attn (fp32, d_out) + Ph (bf16) ---
  softmax_kernel<<<dim3((int)ML), blk, 0, stream>>>(Sh, mask, cvec, attn, Ph);

  // --- Out: per-batch Ph·VWoT^T + bo -> d_out fp32 ---
  gemm8<0><<<dim3(D / 256, QL / 256, B), 512, 131072, stream>>>(
      Ph, VWoT, out, bo, 1.0f, QL, D, KL, 1, (long long)QL * KL,
      (long long)D * KL, (long long)QL * D);
}